// Round 9
// baseline (285.107 us; speedup 1.0000x reference)
//
#include <hip/hip_runtime.h>
#include <hip/hip_bf16.h>

// MultiAgentSEPSNetwork: A=8 agents, E=4096, O=256, H1=H2=1024, H3=512, S=4.
// M = A*E = 32768 rows. Only the seps_idx-selected net per agent is computed.
//
// R17: R13/R15/R16 (73/67.5/79us L2) bracket a finding: at 2 waves/SIMD
// (1 block/CU; per-wave 128x64 acc = 128 regs -> 224 unified/wave) every
// sync refinement saturates ~67us. Fix GEOMETRY not schedule: per-wave
// 64x64 (acc 4x4 = 64 regs, ~116 total) + __launch_bounds__(512,4) ->
// 4 waves/SIMD -> 2 blocks/CU: when one block stalls (vmcnt/barrier), the
// other block's waves feed the MFMA pipe (m114 auto-overlap).
//  - tile 256x128, 8 waves (4M x 2N), BK=32 units, ring-of-3 LDS
//    (3 x 24KB = 72KB/block; 2 blocks = 144KB <= 160).
//  - counted VMCNT(3) per unit (2 units in flight, stage p+2 during p);
//    vmcnt(0) only at last unit. One barrier/unit, SB0 both sides
//    (R15/R16-proven sync shape).
//  - R16's VERIFIED zero-conflict K=32 layout: LDS[r][s16]=G[r][s16^((r>>1)&3)]
//    via pre-swizzled global source (LDS dest linear, rule 21); read slot
//    quad^((l16>>1)&3).
// Chip-wide L2 floors: MFMA 33us, LDS-read ~40us -> predict 48-56us (vs
// 67.5). Diagnostic: VGPR_Count <= 128 and Occupancy ~40% = TLP landed.
// Kept: XCD grid swizzle (grids 1024/1024/512, %8==0), fused prep,
// LDS-transpose epilogue (re-laid: 4 phases x 64 rows, EW=132).

typedef unsigned short u16;
typedef __bf16 bf16x8 __attribute__((ext_vector_type(8)));
typedef float floatx4 __attribute__((ext_vector_type(4)));

__device__ __forceinline__ u16 f2bf(float f) {
    union { float f; unsigned int u; } v; v.f = f;
    unsigned int u = v.u;
    return (u16)((u + 0x7FFFu + ((u >> 16) & 1u)) >> 16);
}

// global -> LDS direct DMA, 16 B/lane. LDS dest = wave-uniform base + lane*16.
__device__ __forceinline__ void load16(const void* g, void* l) {
    __builtin_amdgcn_global_load_lds(
        (const __attribute__((address_space(1))) void*)(unsigned long long)g,
        (__attribute__((address_space(3))) void*)(unsigned int)(unsigned long long)l,
        16, 0, 0);
}

// ---------------- fused prep: x->bf16 + 3 weight transposes ----------------
__global__ __launch_bounds__(256) void prep(
    const float* __restrict__ x, u16* __restrict__ xb,
    const float* __restrict__ W1, u16* __restrict__ w1t,
    const float* __restrict__ W2, u16* __restrict__ w2t,
    const float* __restrict__ W3, u16* __restrict__ w3t) {
    __shared__ float tile[32][33];
    int b = blockIdx.x;
    const int tid = threadIdx.x;
    if (b < 8192) {
        int i = (b * 256 + tid) * 4;
        float4 v = *(const float4*)(x + i);
        ushort4 o;
        o.x = f2bf(v.x); o.y = f2bf(v.y); o.z = f2bf(v.z); o.w = f2bf(v.w);
        *(ushort4*)(xb + i) = o;
        return;
    }
    b -= 8192;
    const float* src; u16* dst; int K, N, n0, k0, s;
    if (b < 1024) {                     // W1 [4][256][1024] -> [4][1024][256]
        s = b >> 8; int r = b & 255;
        K = 256; N = 1024; n0 = (r & 31) * 32; k0 = (r >> 5) * 32;
        src = W1; dst = w1t;
    } else if (b < 5120) {              // W2 [4][1024][1024] -> same^T
        b -= 1024; s = b >> 10; int r = b & 1023;
        K = 1024; N = 1024; n0 = (r & 31) * 32; k0 = (r >> 5) * 32;
        src = W2; dst = w2t;
    } else {                            // W3 [4][1024][512] -> [4][512][1024]
        b -= 5120; s = b >> 9; int r = b & 511;
        K = 1024; N = 512; n0 = (r & 15) * 32; k0 = (r >> 4) * 32;
        src = W3; dst = w3t;
    }
    src += (size_t)s * K * N;
    dst += (size_t)s * N * K;
    const int tx = tid & 31, ty = tid >> 5;
#pragma unroll
    for (int j = 0; j < 32; j += 8)
        tile[ty + j][tx] = src[(size_t)(k0 + ty + j) * N + (n0 + tx)];
    __syncthreads();
#pragma unroll
    for (int j = 0; j < 32; j += 8)
        dst[(size_t)(n0 + ty + j) * K + (k0 + tx)] = f2bf(tile[tx][ty + j]);
}

#define VMCNT(n) asm volatile("s_waitcnt vmcnt(" #n ")" ::: "memory")
#define SB0 __builtin_amdgcn_sched_barrier(0)

// ---- grouped GEMM: 256x128, BK=32 ring-3, counted vmcnt, 2 blocks/CU ----
// C[m,n] = act(A[M,K] @ Wt[s][N,K]^T + bias[s][N]);  s = seps[agent(m)]
// 512 thr = 8 waves (4M x 2N); per-wave C = 64x64 (acc 4x4); 16x16x32 MFMA.
// Unit (24KB): A[256][32] @ off 0, B[128][32] @ off 8192 (u16), 64B rows,
// LDS[r][s16] = G[r][s16 ^ ((r>>1)&3)] (R16-verified, 0 conflicts).
// Per wave per unit: 3 DMAs (2 A + 1 B), 8 ds_read_b128, 16 MFMA.
template <int K, int N, bool RELU, bool OUT_BF16>
__global__ __launch_bounds__(512, 4) void gemm_mlp(
    const u16* __restrict__ Amat, const u16* __restrict__ Wt,
    const float* __restrict__ bias, const int* __restrict__ seps,
    void* __restrict__ outp) {
    constexpr int P = K / 32;                  // K-units
    constexpr int NNB = N / 128;               // n-blocks per m-stripe (8 or 4)
    constexpr int LNB = (NNB == 8) ? 3 : 2;
    constexpr int UNIT = 12288;                // u16 per unit (24KB)
    extern __shared__ u16 lds[];               // 3 units = 72KB dynamic

    const int tid = threadIdx.x;
    const int wave = tid >> 6, lane = tid & 63;
    const int wm = wave >> 1, wn = wave & 1;
    const int quad = lane >> 4, l16 = lane & 15;

    // XCD swizzle: block i -> XCD i%8; all NNB n-blocks of one m-stripe are
    // dispatch-adjacent and share i%8 -> one XCD's L2 holds the A-stripe.
    const int bidx = blockIdx.x;
    const int t = bidx >> 3;
    const int mb = (t >> LNB) * 8 + (bidx & 7);
    const int nb = t & (NNB - 1);
    const int m0 = mb * 256, n0 = nb * 128;

    const int s = seps[m0 >> 12];              // 4096 rows per agent
    const u16* Ab = Amat + (size_t)m0 * K;
    const u16* Bb = Wt + ((size_t)s * N + n0) * K;

    // staging (pre-swizzled global source; LDS dest wave-uniform, linear):
    // lane L -> row-in-16 = L>>2, s16 = L&3 at dest; global chunk
    // g = (L&3) ^ ((L>>3)&3)  => LDS[r][s16] = G[r][s16 ^ ((r>>1)&3)].
    const int rin = lane >> 2;
    const int gsw = (((lane & 3) ^ ((lane >> 3) & 3)) << 3);
    const u16* gA = Ab + (size_t)((wave << 5) + rin) * K + gsw;  // rows w*32+
    const u16* gB = Bb + (size_t)((wave << 4) + rin) * K + gsw;  // rows w*16+
    const unsigned dA = (unsigned)(wave << 10);        // A dest u16 (uniform)
    const unsigned dB = (unsigned)(8192 + (wave << 9));// B dest u16 (uniform)

    auto STAGE = [&](int p, int sb) {
        const int ko = p << 5;                 // k-offset (elems)
        u16* ub = &lds[sb];
        load16(gA + ko, ub + dA);
        load16(gA + (size_t)16 * K + ko, ub + dA + 512);
        load16(gB + ko, ub + dB);
    };

    // fragment reads: addr16 = r*32 + slot*8; slot = quad ^ ((l16>>1)&3).
    const int sA = (quad ^ ((l16 >> 1) & 3)) << 3;
    const int a0 = (((wm << 6) + l16) << 5) + sA;          // A rows wm*64+
    const int b0 = 8192 + (((wn << 6) + l16) << 5) + sA;   // B rows wn*64+

    floatx4 acc[4][4];
#pragma unroll
    for (int i = 0; i < 4; ++i)
#pragma unroll
        for (int j = 0; j < 4; ++j) acc[i][j] = (floatx4){0.f, 0.f, 0.f, 0.f};

    // prologue: stage units 0,1 (6 DMAs/wave in flight).
    STAGE(0, 0); STAGE(1, UNIT);
    int sc = 0;               // compute slot base (cycles 0,UNIT,2*UNIT)
    int ss = 2 * UNIT;        // stage slot base for p+2

    bf16x8 af[4], bf[4];

#pragma unroll 1
    for (int p = 0; p < P; ++p) {
        // retire only unit p's 3 DMAs (unit p+1 stays in flight).
        if (p < P - 1) { VMCNT(3); } else { VMCNT(0); }
        SB0;                                   // pin prev MFMAs above barrier
        __builtin_amdgcn_s_barrier();
        SB0;                                   // no read hoisting above barrier

        if (p + 2 < P) STAGE(p + 2, ss);       // slot of p-1: reads consumed
                                               // behind this barrier (R16 pf)
        const u16* buf = &lds[sc];
        af[0] = *(const bf16x8*)&buf[a0];
#pragma unroll
        for (int nf = 0; nf < 4; ++nf)
            bf[nf] = *(const bf16x8*)&buf[b0 + (nf << 9)];
#pragma unroll
        for (int i = 1; i < 4; ++i)
            af[i] = *(const bf16x8*)&buf[a0 + (i << 9)];

        __builtin_amdgcn_s_setprio(1);
#pragma unroll
        for (int i = 0; i < 4; ++i)
#pragma unroll
            for (int nf = 0; nf < 4; ++nf)
                acc[i][nf] = __builtin_amdgcn_mfma_f32_16x16x32_bf16(
                    af[i], bf[nf], acc[i][nf], 0, 0, 0);
        __builtin_amdgcn_s_setprio(0);

        sc = (sc == 2 * UNIT) ? 0 : sc + UNIT;
        ss = (ss == 2 * UNIT) ? 0 : ss + UNIT;
    }
    __syncthreads();   // all LDS traffic done before epilogue reuse

    // ---- epilogue: 4 phases x 64 rows, LDS transpose, coalesced stores ----
    float* eps = (float*)lds;                  // [64][132] f32 per phase
    constexpr int EW = 132;
    float bv[4];
#pragma unroll
    for (int nf = 0; nf < 4; ++nf)
        bv[nf] = bias[s * N + n0 + (wn << 6) + (nf << 4) + l16];

    const int er = tid >> 3;                   // 0..63 row
    const int cg = tid & 7;                    // 16-f32 col group

#pragma unroll
    for (int ph = 0; ph < 4; ++ph) {
        if (wm == ph) {                        // this wave's 64-row band
#pragma unroll
            for (int i = 0; i < 4; ++i)
#pragma unroll
                for (int nf = 0; nf < 4; ++nf)
#pragma unroll
                    for (int r = 0; r < 4; ++r) {
                        float v = acc[i][nf][r] + bv[nf];
                        if (RELU) v = fmaxf(v, 0.0f);
                        eps[((i << 4) + (quad << 2) + r) * EW +
                            (wn << 6) + (nf << 4) + l16] = v;
                    }
        }
        __syncthreads();
        {
            const int grow = m0 + (ph << 6) + er;
            const float* src = eps + er * EW + (cg << 4);
            float4 v0 = *(const float4*)(src);
            float4 v1 = *(const float4*)(src + 4);
            float4 v2 = *(const float4*)(src + 8);
            float4 v3 = *(const float4*)(src + 12);
            if (OUT_BF16) {
                u16* dst = (u16*)outp + (size_t)grow * N + n0 + (cg << 4);
                ushort4 o0, o1, o2, o3;
                o0.x = f2bf(v0.x); o0.y = f2bf(v0.y); o0.z = f2bf(v0.z); o0.w = f2bf(v0.w);
                o1.x = f2bf(v1.x); o1.y = f2bf(v1.y); o1.z = f2bf(v1.z); o1.w = f2bf(v1.w);
                o2.x = f2bf(v2.x); o2.y = f2bf(v2.y); o2.z = f2bf(v2.z); o2.w = f2bf(v2.w);
                o3.x = f2bf(v3.x); o3.y = f2bf(v3.y); o3.z = f2bf(v3.z); o3.w = f2bf(v3.w);
                *(ushort4*)(dst) = o0;
                *(ushort4*)(dst + 4) = o1;
                *(ushort4*)(dst + 8) = o2;
                *(ushort4*)(dst + 12) = o3;
            } else {
                float* dst = (float*)outp + (size_t)grow * N + n0 + (cg << 4);
                *(float4*)(dst) = v0;
                *(float4*)(dst + 4) = v1;
                *(float4*)(dst + 8) = v2;
                *(float4*)(dst + 12) = v3;
            }
        }
        __syncthreads();
    }
}

extern "C" void kernel_launch(void* const* d_in, const int* in_sizes, int n_in,
                              void* d_out, int out_size, void* d_ws, size_t ws_size,
                              hipStream_t stream) {
    const float* x  = (const float*)d_in[0];
    const float* W1 = (const float*)d_in[1];
    const float* b1 = (const float*)d_in[2];
    const float* W2 = (const float*)d_in[3];
    const float* b2 = (const float*)d_in[4];
    const float* W3 = (const float*)d_in[5];
    const float* b3 = (const float*)d_in[6];
    const int* seps = (const int*)d_in[7];

    char* ws = (char*)d_ws;
    u16* w1t = (u16*)(ws);                    //  2 MB: [4][1024][256]
    u16* w2t = (u16*)(ws + (2ull << 20));     //  8 MB: [4][1024][1024]
    u16* w3t = (u16*)(ws + (10ull << 20));    //  4 MB: [4][512][1024]
    u16* xb  = (u16*)(ws + (14ull << 20));    // 16 MB: [32768][256]
    u16* h1  = (u16*)(ws + (30ull << 20));    // 64 MB: [32768][1024]
    u16* h2  = (u16*)(ws + (94ull << 20));    // 64 MB: [32768][1024]

    // 72 KB dynamic LDS opt-in (host-side, once).
    static int attr_once = []() {
        auto k1 = gemm_mlp<256, 1024, true, true>;
        auto k2 = gemm_mlp<1024, 1024, true, true>;
        auto k3 = gemm_mlp<1024, 512, false, false>;
        hipFuncSetAttribute(reinterpret_cast<const void*>(k1),
                            hipFuncAttributeMaxDynamicSharedMemorySize, 73728);
        hipFuncSetAttribute(reinterpret_cast<const void*>(k2),
                            hipFuncAttributeMaxDynamicSharedMemorySize, 73728);
        hipFuncSetAttribute(reinterpret_cast<const void*>(k3),
                            hipFuncAttributeMaxDynamicSharedMemorySize, 73728);
        return 0;
    }();
    (void)attr_once;

    prep<<<15360, 256, 0, stream>>>(x, xb, W1, w1t, W2, w2t, W3, w3t);

    // L1: [32768,256]@[256,1024]^T +b1, relu -> h1 (bf16)
    gemm_mlp<256, 1024, true, true><<<1024, 512, 73728, stream>>>(xb, w1t, b1, seps, h1);
    // L2: [32768,1024]@[1024,1024]^T +b2, relu -> h2 (bf16)
    gemm_mlp<1024, 1024, true, true><<<1024, 512, 73728, stream>>>(h1, w2t, b2, seps, h2);
    // L3: [32768,1024]@[1024,512]^T +b3 -> out (f32)
    gemm_mlp<1024, 512, false, false><<<512, 512, 73728, stream>>>(h2, w3t, b3, seps, d_out);
}